// Round 1
// baseline (191.884 us; speedup 1.0000x reference)
//
#include <hip/hip_runtime.h>

#define TW 32
#define TH 32
#define HALO 5
#define KS 11
#define IW (TW + 2*HALO)    // 42
#define IH (TH + 2*HALO)    // 42
#define LDSS (IW + 2)       // 44, pad to avoid pathological strides

__global__ __launch_bounds__(256) void ssim_tile_kernel(
    const float* __restrict__ pred, const float* __restrict__ target,
    const float* __restrict__ window, float* __restrict__ partial,
    int H, int W)
{
    __shared__ float sg[KS];
    __shared__ float sp[IH][LDSS];
    __shared__ float st[IH][LDSS];
    __shared__ float hp[IH][TW];
    __shared__ float ht[IH][TW];
    __shared__ float hpp[IH][TW];
    __shared__ float htt[IH][TW];
    __shared__ float hpt[IH][TW];
    __shared__ float wsum[4];

    const int tid = threadIdx.x;

    // Recover separable 1-D Gaussian: g[i] = sum_j w2d[i][j]  (since sum(g)=1)
    if (tid < KS) {
        float s = 0.f;
        #pragma unroll
        for (int j = 0; j < KS; ++j) s += window[tid * KS + j];
        sg[tid] = s;
    }

    const int bc  = blockIdx.z;              // b*C + c
    const int ty0 = blockIdx.y * TH;
    const int tx0 = blockIdx.x * TW;
    const float* p0 = pred   + (size_t)bc * H * W;
    const float* t0 = target + (size_t)bc * H * W;

    // Load halo tiles (zero padding outside image = SAME/zero-pad conv)
    for (int i = tid; i < IH * IW; i += 256) {
        int r = i / IW, c = i % IW;
        int gy = ty0 + r - HALO, gx = tx0 + c - HALO;
        float pv = 0.f, tv = 0.f;
        if (gy >= 0 && gy < H && gx >= 0 && gx < W) {
            size_t idx = (size_t)gy * W + gx;
            pv = p0[idx];
            tv = t0[idx];
        }
        sp[r][c] = pv;
        st[r][c] = tv;
    }
    __syncthreads();

    // Horizontal pass: 5 quantities, 11 taps
    for (int i = tid; i < IH * TW; i += 256) {
        int r = i / TW, c = i % TW;
        float a0 = 0.f, a1 = 0.f, a2 = 0.f, a3 = 0.f, a4 = 0.f;
        #pragma unroll
        for (int j = 0; j < KS; ++j) {
            float w = sg[j];
            float p = sp[r][c + j];
            float t = st[r][c + j];
            a0 += w * p;
            a1 += w * t;
            a2 += w * p * p;
            a3 += w * t * t;
            a4 += w * p * t;
        }
        hp[r][c]  = a0;
        ht[r][c]  = a1;
        hpp[r][c] = a2;
        htt[r][c] = a3;
        hpt[r][c] = a4;
    }
    __syncthreads();

    // Vertical pass + SSIM map + local accumulation
    const float C1 = 1e-4f, C2 = 9e-4f;
    float acc = 0.f;
    for (int i = tid; i < TH * TW; i += 256) {
        int y = i / TW, x = i % TW;
        float m1 = 0.f, m2 = 0.f, s11 = 0.f, s22 = 0.f, s12 = 0.f;
        #pragma unroll
        for (int j = 0; j < KS; ++j) {
            float w = sg[j];
            m1  += w * hp[y + j][x];
            m2  += w * ht[y + j][x];
            s11 += w * hpp[y + j][x];
            s22 += w * htt[y + j][x];
            s12 += w * hpt[y + j][x];
        }
        float mu1s = m1 * m1, mu2s = m2 * m2, mu12 = m1 * m2;
        float sig1 = s11 - mu1s, sig2 = s22 - mu2s, sig12 = s12 - mu12;
        float num = (2.f * mu12 + C1) * (2.f * sig12 + C2);
        float den = (mu1s + mu2s + C1) * (sig1 + sig2 + C2);
        acc += num / den;
    }

    // Block reduction: wave shfl then cross-wave via LDS
    #pragma unroll
    for (int off = 32; off > 0; off >>= 1) acc += __shfl_down(acc, off, 64);
    int wid = tid >> 6, lane = tid & 63;
    if (lane == 0) wsum[wid] = acc;
    __syncthreads();
    if (tid == 0) {
        float s = wsum[0] + wsum[1] + wsum[2] + wsum[3];
        atomicAdd(partial, s);
    }
}

__global__ void ssim_final_kernel(const float* __restrict__ partial,
                                  float* __restrict__ out, float invN)
{
    out[0] = 1.f - partial[0] * invN;
}

extern "C" void kernel_launch(void* const* d_in, const int* in_sizes, int n_in,
                              void* d_out, int out_size, void* d_ws, size_t ws_size,
                              hipStream_t stream) {
    const float* pred   = (const float*)d_in[0];
    const float* target = (const float*)d_in[1];
    const float* window = (const float*)d_in[2];
    float* out = (float*)d_out;
    float* partial = (float*)d_ws;

    const int B = 16, C = 3, H = 512, W = 512;
    const float invN = 1.0f / ((float)B * C * H * W);

    hipMemsetAsync(partial, 0, sizeof(float), stream);

    dim3 grid(W / TW, H / TH, B * C);   // 16 x 16 x 48
    dim3 block(256);
    ssim_tile_kernel<<<grid, block, 0, stream>>>(pred, target, window, partial, H, W);
    ssim_final_kernel<<<1, 1, 0, stream>>>(partial, out, invN);
}

// Round 2
// 187.130 us; speedup vs baseline: 1.0254x; 1.0254x over previous
//
#include <hip/hip_runtime.h>
#include <math.h>

#define TW 32
#define TH 32
#define HALO 5
#define KS 11
#define IH (TH + 2*HALO)        // 42 rows staged
#define IW (TW + 2*HALO)        // 42 cols staged
#define SST 44                  // stage row stride in floats (176 B, 16B-aligned)
#define HQT 44                  // hq row stride in floats

struct G11 { float g[KS]; };

__global__ __launch_bounds__(256, 4) void ssim_tile_kernel(
    const float* __restrict__ pred, const float* __restrict__ target,
    float* __restrict__ partial, G11 gw)
{
    __shared__ float sp[IH][SST];
    __shared__ float st[IH][SST];
    __shared__ float hq[5][TW][HQT];   // transposed: [quantity][x][r]
    __shared__ float wsum[4];

    const int tid = threadIdx.x;
    const int bc  = blockIdx.z;
    const int ty0 = blockIdx.y * TH;
    const int tx0 = blockIdx.x * TW;
    const float* p0 = pred   + (size_t)bc * (512 * 512);
    const float* t0 = target + (size_t)bc * (512 * 512);

    // ---- stage raw p/t tiles with zero halo ----
    for (int i = tid; i < IH * IW; i += 256) {
        int r = i / IW, c = i - r * IW;
        int gy = ty0 + r - HALO, gx = tx0 + c - HALO;
        float pv = 0.f, tv = 0.f;
        if (gy >= 0 && gy < 512 && gx >= 0 && gx < 512) {
            size_t idx = (size_t)gy * 512 + gx;
            pv = p0[idx];
            tv = t0[idx];
        }
        sp[r][c] = pv;
        st[r][c] = tv;
    }
    __syncthreads();

    // ---- horizontal pass: thread = (row rr, 4-col group g8) ----
    {
        const int g8 = tid & 7;
        const int r0 = tid >> 3;           // 0..31
        const int c0 = g8 * 4;
        for (int rr = r0; rr < IH; rr += 32) {
            const float4 P0 = *(const float4*)&sp[rr][c0];
            const float4 P1 = *(const float4*)&sp[rr][c0 + 4];
            const float4 P2 = *(const float4*)&sp[rr][c0 + 8];
            const float4 P3 = *(const float4*)&sp[rr][c0 + 12];
            const float4 T0 = *(const float4*)&st[rr][c0];
            const float4 T1 = *(const float4*)&st[rr][c0 + 4];
            const float4 T2 = *(const float4*)&st[rr][c0 + 8];
            const float4 T3 = *(const float4*)&st[rr][c0 + 12];
            const float p[16] = {P0.x,P0.y,P0.z,P0.w, P1.x,P1.y,P1.z,P1.w,
                                 P2.x,P2.y,P2.z,P2.w, P3.x,P3.y,P3.z,P3.w};
            const float t[16] = {T0.x,T0.y,T0.z,T0.w, T1.x,T1.y,T1.z,T1.w,
                                 T2.x,T2.y,T2.z,T2.w, T3.x,T3.y,T3.z,T3.w};
            float a0[4] = {0.f,0.f,0.f,0.f};
            float a1[4] = {0.f,0.f,0.f,0.f};
            float a2[4] = {0.f,0.f,0.f,0.f};
            float a3[4] = {0.f,0.f,0.f,0.f};
            float a4[4] = {0.f,0.f,0.f,0.f};
            #pragma unroll
            for (int j = 0; j < KS; ++j) {
                const float w = gw.g[j];
                #pragma unroll
                for (int i = 0; i < 4; ++i) {
                    const float v = p[i + j];
                    const float u = t[i + j];
                    const float wv = w * v;
                    const float wu = w * u;
                    a0[i] += wv;
                    a1[i] += wu;
                    a2[i] = fmaf(wv, v, a2[i]);
                    a3[i] = fmaf(wu, u, a3[i]);
                    a4[i] = fmaf(wv, u, a4[i]);
                }
            }
            #pragma unroll
            for (int i = 0; i < 4; ++i) {
                hq[0][c0 + i][rr] = a0[i];
                hq[1][c0 + i][rr] = a1[i];
                hq[2][c0 + i][rr] = a2[i];
                hq[3][c0 + i][rr] = a3[i];
                hq[4][c0 + i][rr] = a4[i];
            }
        }
    }
    __syncthreads();

    // ---- vertical pass + SSIM map: thread = (col x, 4-row group) ----
    const float C1 = 1e-4f, C2 = 9e-4f;
    float acc = 0.f;
    {
        const int x  = tid & 31;
        const int y0 = (tid >> 5) * 4;
        float m[5][4];
        #pragma unroll
        for (int q = 0; q < 5; ++q) {
            const float4 A = *(const float4*)&hq[q][x][y0];
            const float4 B = *(const float4*)&hq[q][x][y0 + 4];
            const float4 Cv = *(const float4*)&hq[q][x][y0 + 8];
            const float4 D = *(const float4*)&hq[q][x][y0 + 12];
            const float h[16] = {A.x,A.y,A.z,A.w, B.x,B.y,B.z,B.w,
                                 Cv.x,Cv.y,Cv.z,Cv.w, D.x,D.y,D.z,D.w};
            #pragma unroll
            for (int i = 0; i < 4; ++i) {
                float s = 0.f;
                #pragma unroll
                for (int j = 0; j < KS; ++j)
                    s = fmaf(gw.g[j], h[i + j], s);
                m[q][i] = s;
            }
        }
        #pragma unroll
        for (int i = 0; i < 4; ++i) {
            const float m1 = m[0][i], m2 = m[1][i];
            const float mu1s = m1 * m1, mu2s = m2 * m2, mu12 = m1 * m2;
            const float sig1 = m[2][i] - mu1s;
            const float sig2 = m[3][i] - mu2s;
            const float sig12 = m[4][i] - mu12;
            const float num = (2.f * mu12 + C1) * (2.f * sig12 + C2);
            const float den = (mu1s + mu2s + C1) * (sig1 + sig2 + C2);
            acc += num / den;
        }
    }

    // ---- block reduction ----
    #pragma unroll
    for (int off = 32; off > 0; off >>= 1) acc += __shfl_down(acc, off, 64);
    const int wid = tid >> 6, lane = tid & 63;
    if (lane == 0) wsum[wid] = acc;
    __syncthreads();
    if (tid == 0) {
        atomicAdd(partial, wsum[0] + wsum[1] + wsum[2] + wsum[3]);
    }
}

__global__ void ssim_final_kernel(const float* __restrict__ partial,
                                  float* __restrict__ out, float invN)
{
    out[0] = 1.f - partial[0] * invN;
}

extern "C" void kernel_launch(void* const* d_in, const int* in_sizes, int n_in,
                              void* d_out, int out_size, void* d_ws, size_t ws_size,
                              hipStream_t stream) {
    const float* pred   = (const float*)d_in[0];
    const float* target = (const float*)d_in[1];
    float* out = (float*)d_out;
    float* partial = (float*)d_ws;

    const int B = 16, C = 3, H = 512, W = 512;
    const float invN = 1.0f / ((float)B * C * H * W);

    // separable 1-D Gaussian, same formula as reference (sigma=1.5, 11 taps)
    G11 gw;
    {
        float s = 0.f;
        for (int i = 0; i < KS; ++i) {
            double e = exp(-((double)((i - 5) * (i - 5))) / (2.0 * 1.5 * 1.5));
            gw.g[i] = (float)e;
            s += gw.g[i];
        }
        for (int i = 0; i < KS; ++i) gw.g[i] /= s;
    }

    hipMemsetAsync(partial, 0, sizeof(float), stream);

    dim3 grid(W / TW, H / TH, B * C);   // 16 x 16 x 48
    dim3 block(256);
    ssim_tile_kernel<<<grid, block, 0, stream>>>(pred, target, partial, gw);
    ssim_final_kernel<<<1, 1, 0, stream>>>(partial, out, invN);
}

// Round 3
// 165.087 us; speedup vs baseline: 1.1623x; 1.1335x over previous
//
#include <hip/hip_runtime.h>
#include <math.h>

#define KS 11
#define CHUNK 64      // output rows per block
#define IMW 512
#define IMH 512

struct G11 { float g[KS]; };

// Each thread owns one output column x and streams CHUNK rows downward.
// 11-deep register ring of the 5 horizontal-conv quantities; all ring
// indices are compile-time constants via the unroll-by-11 phase trick.
__global__ __launch_bounds__(256, 3) void ssim_col_kernel(
    const float* __restrict__ pred, const float* __restrict__ target,
    float* __restrict__ partial, G11 gw)
{
    const int tid = threadIdx.x;
    const int x   = blockIdx.x * 256 + tid;       // output column, 0..511
    const int y0  = blockIdx.y * CHUNK;           // first output row
    const int bc  = blockIdx.z;
    const float* pimg = pred   + (size_t)bc * (IMH * IMW);
    const float* timg = target + (size_t)bc * (IMH * IMW);

    // Per-thread clamped byte offsets + pre-masked horizontal weights.
    // Out-of-image columns contribute 0 via wh[j]=0 (zero-pad semantics),
    // address clamp keeps every load in-bounds. Zero per-row cost.
    int   voff[KS];
    float wh[KS];
    #pragma unroll
    for (int j = 0; j < KS; ++j) {
        const int cx = x - 5 + j;
        const int ok = (cx >= 0 && cx < IMW);
        const int cc = cx < 0 ? 0 : (cx >= IMW ? IMW - 1 : cx);
        voff[j] = cc * 4;
        wh[j]   = ok ? gw.g[j] : 0.f;
    }

    // ring of horizontal conv results (5 quantities x 11 rows)
    float h0[KS], h1[KS], h2[KS], h3[KS], h4[KS];

    // Ingest input row (y0 - 5 + K_OFF) into ring slot S (S must be a
    // compile-time constant at every expansion).
#define INGEST(S, K_OFF)                                                    \
    {                                                                       \
        const int yi = y0 - 5 + (K_OFF);                                    \
        float a0 = 0.f, a1 = 0.f, a2 = 0.f, a3 = 0.f, a4 = 0.f;             \
        if ((unsigned)yi < (unsigned)IMH) {                                 \
            const char* prow = (const char*)(pimg + (size_t)yi * IMW);      \
            const char* trow = (const char*)(timg + (size_t)yi * IMW);      \
            float pj[KS], tj[KS];                                           \
            _Pragma("unroll")                                               \
            for (int j = 0; j < KS; ++j) {                                  \
                pj[j] = *(const float*)(prow + voff[j]);                    \
                tj[j] = *(const float*)(trow + voff[j]);                    \
            }                                                               \
            _Pragma("unroll")                                               \
            for (int j = 0; j < KS; ++j) {                                  \
                const float wv = wh[j] * pj[j];                             \
                const float wu = wh[j] * tj[j];                             \
                a0 += wv; a1 += wu;                                         \
                a2 = fmaf(wv, pj[j], a2);                                   \
                a3 = fmaf(wu, tj[j], a3);                                   \
                a4 = fmaf(wv, tj[j], a4);                                   \
            }                                                               \
        }                                                                   \
        h0[S] = a0; h1[S] = a1; h2[S] = a2; h3[S] = a3; h4[S] = a4;         \
    }

    // Prologue: fill slots 0..9 with rows y0-5 .. y0+4.
    #pragma unroll
    for (int i = 0; i < 10; ++i) {
        INGEST(i, i)
    }

    const float C1 = 1e-4f, C2 = 9e-4f;
    float acc = 0.f;

    // Main: for output row y0+k, ingest row y0+5+k into slot (k+10)%11,
    // vertical taps j hit slot (k+j)%11. k0 is a multiple of 11 so all
    // slots depend only on kk (compile-time).
    for (int k0 = 0; k0 < CHUNK; k0 += KS) {
        #pragma unroll
        for (int kk = 0; kk < KS; ++kk) {
            const int k = k0 + kk;
            if (k < CHUNK) {
                INGEST((kk + 10) % KS, k + 10)

                float m1 = 0.f, m2 = 0.f, s11 = 0.f, s22 = 0.f, s12 = 0.f;
                #pragma unroll
                for (int j = 0; j < KS; ++j) {
                    const float w = gw.g[j];
                    m1  = fmaf(w, h0[(kk + j) % KS], m1);
                    m2  = fmaf(w, h1[(kk + j) % KS], m2);
                    s11 = fmaf(w, h2[(kk + j) % KS], s11);
                    s22 = fmaf(w, h3[(kk + j) % KS], s22);
                    s12 = fmaf(w, h4[(kk + j) % KS], s12);
                }
                const float mu1s = m1 * m1, mu2s = m2 * m2, mu12 = m1 * m2;
                const float sg1  = s11 - mu1s;
                const float sg2  = s22 - mu2s;
                const float sg12 = s12 - mu12;
                const float num = (2.f * mu12 + C1) * (2.f * sg12 + C2);
                const float den = (mu1s + mu2s + C1) * (sg1 + sg2 + C2);
                acc += num * __builtin_amdgcn_rcpf(den);
            }
        }
    }
#undef INGEST

    // Block reduction: wave shfl, then cross-wave via tiny LDS.
    __shared__ float wsum[4];
    #pragma unroll
    for (int off = 32; off > 0; off >>= 1) acc += __shfl_down(acc, off, 64);
    const int wid = tid >> 6, lane = tid & 63;
    if (lane == 0) wsum[wid] = acc;
    __syncthreads();
    if (tid == 0) {
        atomicAdd(partial, wsum[0] + wsum[1] + wsum[2] + wsum[3]);
    }
}

__global__ void ssim_final_kernel(const float* __restrict__ partial,
                                  float* __restrict__ out, float invN)
{
    out[0] = 1.f - partial[0] * invN;
}

extern "C" void kernel_launch(void* const* d_in, const int* in_sizes, int n_in,
                              void* d_out, int out_size, void* d_ws, size_t ws_size,
                              hipStream_t stream) {
    const float* pred   = (const float*)d_in[0];
    const float* target = (const float*)d_in[1];
    float* out = (float*)d_out;
    float* partial = (float*)d_ws;

    const int B = 16, C = 3;
    const float invN = 1.0f / ((float)B * C * IMH * IMW);

    // separable 1-D Gaussian, same formula as reference (sigma=1.5, 11 taps)
    G11 gw;
    {
        float s = 0.f;
        for (int i = 0; i < KS; ++i) {
            double e = exp(-((double)((i - 5) * (i - 5))) / (2.0 * 1.5 * 1.5));
            gw.g[i] = (float)e;
            s += gw.g[i];
        }
        for (int i = 0; i < KS; ++i) gw.g[i] /= s;
    }

    hipMemsetAsync(partial, 0, sizeof(float), stream);

    dim3 grid(IMW / 256, IMH / CHUNK, B * C);   // 2 x 8 x 48 = 768 blocks
    dim3 block(256);
    ssim_col_kernel<<<grid, block, 0, stream>>>(pred, target, partial, gw);
    ssim_final_kernel<<<1, 1, 0, stream>>>(partial, out, invN);
}

// Round 4
// 112.830 us; speedup vs baseline: 1.7006x; 1.4631x over previous
//
#include <hip/hip_runtime.h>
#include <math.h>

#define KS 11
#define CHUNK 33      // output rows per block = 3 x 11 (keeps ring phases static)
#define GRIDY 16      // 16*33 = 528 >= 512; tail rows masked out of the sum
#define IMW 512
#define IMH 512

struct G11 { float g[KS]; };

// Each thread owns one output column x and streams CHUNK rows downward.
// 11-deep register ring of the 5 horizontal-conv quantities; every ring
// index is a compile-time constant (phase trick, CHUNK % 11 == 0).
__global__ __launch_bounds__(256, 1) void ssim_col_kernel(
    const float* __restrict__ pred, const float* __restrict__ target,
    float* __restrict__ partial, G11 gw)
{
    const int tid = threadIdx.x;
    const int x   = blockIdx.x * 256 + tid;       // output column, 0..511
    const int y0  = blockIdx.y * CHUNK;           // first output row
    const int bc  = blockIdx.z;
    const float* pimg = pred   + (size_t)bc * (IMH * IMW);
    const float* timg = target + (size_t)bc * (IMH * IMW);

    // Per-thread clamped byte offsets + pre-masked horizontal weights.
    // Out-of-image columns contribute 0 via wh[j]=0 (zero-pad semantics);
    // the address clamp keeps every load in-bounds. Zero per-row cost.
    int   voff[KS];
    float wh[KS];
    #pragma unroll
    for (int j = 0; j < KS; ++j) {
        const int cx = x - 5 + j;
        const int ok = (cx >= 0 && cx < IMW);
        const int cc = cx < 0 ? 0 : (cx >= IMW ? IMW - 1 : cx);
        voff[j] = cc * 4;
        wh[j]   = ok ? gw.g[j] : 0.f;
    }

    // ring of horizontal conv results (5 quantities x 11 rows)
    float h0[KS], h1[KS], h2[KS], h3[KS], h4[KS];

    // Ingest input row YI into ring slot S (S is a compile-time constant
    // at every expansion; YI may be a runtime value).
#define INGEST(S, YI)                                                       \
    {                                                                       \
        const int yi = (YI);                                                \
        float a0 = 0.f, a1 = 0.f, a2 = 0.f, a3 = 0.f, a4 = 0.f;             \
        if ((unsigned)yi < (unsigned)IMH) {                                 \
            const char* prow = (const char*)(pimg + (size_t)yi * IMW);      \
            const char* trow = (const char*)(timg + (size_t)yi * IMW);      \
            float pj[KS], tj[KS];                                           \
            _Pragma("unroll")                                               \
            for (int j = 0; j < KS; ++j) {                                  \
                pj[j] = *(const float*)(prow + voff[j]);                    \
                tj[j] = *(const float*)(trow + voff[j]);                    \
            }                                                               \
            _Pragma("unroll")                                               \
            for (int j = 0; j < KS; ++j) {                                  \
                const float wv = wh[j] * pj[j];                             \
                const float wu = wh[j] * tj[j];                             \
                a0 += wv; a1 += wu;                                         \
                a2 = fmaf(wv, pj[j], a2);                                   \
                a3 = fmaf(wu, tj[j], a3);                                   \
                a4 = fmaf(wv, tj[j], a4);                                   \
            }                                                               \
        }                                                                   \
        h0[S] = a0; h1[S] = a1; h2[S] = a2; h3[S] = a3; h4[S] = a4;         \
    }

    // Prologue: fill slots 0..9 with input rows y0-5 .. y0+4.
    #pragma unroll
    for (int i = 0; i < 10; ++i) {
        INGEST(i, y0 - 5 + i)
    }

    const float C1 = 1e-4f, C2 = 9e-4f;
    float acc = 0.f;

    // Main: output row y = y0+k0+kk; ingest input row y+5 into slot
    // (kk+10)%11; vertical tap j reads slot (kk+j)%11. k0 is a multiple
    // of 11, so all slots depend only on kk (compile-time).
    for (int k0 = 0; k0 < CHUNK; k0 += KS) {
        #pragma unroll
        for (int kk = 0; kk < KS; ++kk) {
            const int k = k0 + kk;
            INGEST((kk + 10) % KS, y0 + k + 5)

            float m1 = 0.f, m2 = 0.f, s11 = 0.f, s22 = 0.f, s12 = 0.f;
            #pragma unroll
            for (int j = 0; j < KS; ++j) {
                const float w = gw.g[j];
                m1  = fmaf(w, h0[(kk + j) % KS], m1);
                m2  = fmaf(w, h1[(kk + j) % KS], m2);
                s11 = fmaf(w, h2[(kk + j) % KS], s11);
                s22 = fmaf(w, h3[(kk + j) % KS], s22);
                s12 = fmaf(w, h4[(kk + j) % KS], s12);
            }
            const float mu1s = m1 * m1, mu2s = m2 * m2, mu12 = m1 * m2;
            const float sg1  = s11 - mu1s;
            const float sg2  = s22 - mu2s;
            const float sg12 = s12 - mu12;
            const float num = (2.f * mu12 + C1) * (2.f * sg12 + C2);
            const float den = (mu1s + mu2s + C1) * (sg1 + sg2 + C2);
            const float val = num * __builtin_amdgcn_rcpf(den);
            // mask output rows beyond the image (blocks 15 covers 495..527)
            acc += (y0 + k < IMH) ? val : 0.f;
        }
    }
#undef INGEST

    // Block reduction: wave shfl, then cross-wave via tiny LDS.
    __shared__ float wsum[4];
    #pragma unroll
    for (int off = 32; off > 0; off >>= 1) acc += __shfl_down(acc, off, 64);
    const int wid = tid >> 6, lane = tid & 63;
    if (lane == 0) wsum[wid] = acc;
    __syncthreads();
    if (tid == 0) {
        atomicAdd(partial, wsum[0] + wsum[1] + wsum[2] + wsum[3]);
    }
}

__global__ void ssim_final_kernel(const float* __restrict__ partial,
                                  float* __restrict__ out, float invN)
{
    out[0] = 1.f - partial[0] * invN;
}

extern "C" void kernel_launch(void* const* d_in, const int* in_sizes, int n_in,
                              void* d_out, int out_size, void* d_ws, size_t ws_size,
                              hipStream_t stream) {
    const float* pred   = (const float*)d_in[0];
    const float* target = (const float*)d_in[1];
    float* out = (float*)d_out;
    float* partial = (float*)d_ws;

    const int B = 16, C = 3;
    const float invN = 1.0f / ((float)B * C * IMH * IMW);

    // separable 1-D Gaussian, same formula as reference (sigma=1.5, 11 taps)
    G11 gw;
    {
        float s = 0.f;
        for (int i = 0; i < KS; ++i) {
            double e = exp(-((double)((i - 5) * (i - 5))) / (2.0 * 1.5 * 1.5));
            gw.g[i] = (float)e;
            s += gw.g[i];
        }
        for (int i = 0; i < KS; ++i) gw.g[i] /= s;
    }

    hipMemsetAsync(partial, 0, sizeof(float), stream);

    dim3 grid(IMW / 256, GRIDY, B * C);   // 2 x 16 x 48 = 1536 blocks
    dim3 block(256);
    ssim_col_kernel<<<grid, block, 0, stream>>>(pred, target, partial, gw);
    ssim_final_kernel<<<1, 1, 0, stream>>>(partial, out, invN);
}